// Round 19
// baseline (233.900 us; speedup 1.0000x reference)
//
#include <hip/hip_runtime.h>
#include <hip/hip_bf16.h>
#include <cstdint>
#include <cstddef>

#define EPS_IN 1e-5f

typedef __attribute__((ext_vector_type(8))) short short8;
typedef __attribute__((ext_vector_type(4))) float floatx4;
typedef __attribute__((ext_vector_type(8))) unsigned short ushort8;
typedef __attribute__((ext_vector_type(4))) unsigned int uint4v;
typedef __attribute__((address_space(3))) unsigned int lds_uint;
typedef __attribute__((address_space(1))) const unsigned int glb_uint;

__device__ __forceinline__ unsigned short f2bf(float f) {
    unsigned int u = __float_as_uint(f);
    u += 0x7FFFu + ((u >> 16) & 1u);     // RNE
    return (unsigned short)(u >> 16);
}
__device__ __forceinline__ float bf2f(unsigned short s) {
    return __uint_as_float((unsigned int)s << 16);
}
__device__ __forceinline__ float bflo(unsigned int u) {
    return __uint_as_float(u << 16);
}
__device__ __forceinline__ float bfhi(unsigned int u) {
    return __uint_as_float(u & 0xFFFF0000u);
}

// Composed double instance-norm affine from raw (sum, sumsq).
__device__ __forceinline__ void composed_norm(float s, float q, float HW,
                                              float& A, float& B) {
    float m1 = s / HW;
    float v1 = q / HW - m1 * m1;
    float r1 = rsqrtf(v1 + EPS_IN);
    float a1 = 1.f + r1;
    float b1 = -m1 * r1;
    float r2 = rsqrtf(a1 * a1 * v1 + EPS_IN);
    float a2 = 1.f + r2;
    A = a1 * a2;
    B = a2 * b1 - m1 * r2;
}

// ---------------------------------------------------------------------------
// prologue helpers
// ---------------------------------------------------------------------------
__device__ __forceinline__ void border_zero(unsigned short* buf, int C, int H, int W, int idx) {
    int Hp = H + 2, Wp = W + 2;
    int cg8 = C >> 3;
    int cg = idx % cg8;
    int bi = idx / cg8;
    int y, x;
    if (bi < Wp) { y = 0; x = bi; }
    else if (bi < 2 * Wp) { y = Hp - 1; x = bi - Wp; }
    else {
        int k = bi - 2 * Wp;
        y = 1 + (k >> 1);
        x = (k & 1) ? (Wp - 1) : 0;
    }
    ushort8 z = {0, 0, 0, 0, 0, 0, 0, 0};
    *(ushort8*)&buf[((size_t)y * Wp + x) * C + cg * 8] = z;
}

__device__ __forceinline__ void reorder_one(const float* w, unsigned short* dst,
                                            int O, int C, int j) {
    int cg8 = C >> 3;
    int cg = j % cg8;
    int o = (j / cg8) % O;
    int tap = j / (cg8 * O);
    ushort8 v;
#pragma unroll
    for (int i = 0; i < 8; i++)
        v[i] = f2bf(w[((size_t)o * C + cg * 8 + i) * 9 + tap]);
    *(ushort8*)&dst[((size_t)tap * O + o) * C + cg * 8] = v;
}
__device__ __forceinline__ void stack_one(const float* w, unsigned short* dst,
                                          int C, int O, int j) {
    int cg8 = C >> 3;
    int cg = j % cg8;
    int o = (j / cg8) % O;
    int tap = j / (cg8 * O);
    ushort8 v;
#pragma unroll
    for (int i = 0; i < 8; i++)
        v[i] = f2bf(w[((size_t)(cg * 8 + i) * O + o) * 9 + tap]);
    *(ushort8*)&dst[((size_t)tap * O + o) * C + cg * 8] = v;
}

__device__ __forceinline__ void pad_one(const float* in, unsigned short* xp,
                                        int C, int H, int W, int t) {
    int HW = H * W;
    int p = t % HW;
    int cg = t / HW;
    int y = p / W, x = p % W;
    ushort8 v;
#pragma unroll
    for (int i = 0; i < 8; i++)
        v[i] = f2bf(in[(size_t)(cg * 8 + i) * HW + p]);
    *(ushort8*)&xp[((size_t)(y + 1) * (W + 2) + (x + 1)) * C + cg * 8] = v;
}

// ---------------------------------------------------------------------------
// PROLOGUE mega-kernel (r16-proven).
// ---------------------------------------------------------------------------
__global__ void prologue_kernel(uint4v* __restrict__ statz,
                                unsigned short* __restrict__ xp2,
                                unsigned short* __restrict__ xp1,
                                const float* __restrict__ w_adj2, unsigned short* __restrict__ Wr2,
                                const float* __restrict__ w_adj1, unsigned short* __restrict__ Wr1,
                                const float* __restrict__ w_p16, unsigned short* __restrict__ Wt16,
                                const float* __restrict__ w_p20, unsigned short* __restrict__ Wt20,
                                const float* __restrict__ ef2, const float* __restrict__ ef1,
                                const float* __restrict__ x, float2* __restrict__ statX) {
    __shared__ float ss[4], sq[4];
    int b = blockIdx.x;
    if (b < 68) {
        int t = b * 256 + threadIdx.x;
        const int NZ = 864;
        const int N2 = 516 * 16;
        const int N1 = 1028 * 8;
        if (t < NZ) {
            uint4v z = {0u, 0u, 0u, 0u};
            statz[t] = z;
        } else if (t < NZ + N2) {
            border_zero(xp2, 128, 128, 128, t - NZ);
        } else if (t < NZ + N2 + N1) {
            border_zero(xp1, 64, 256, 256, t - NZ - N2);
        }
    } else if (b < 428) {
        int t = (b - 68) * 256 + threadIdx.x;
        if (t < 36864) reorder_one(w_adj2, Wr2, 256, 128, t);
        else if (t < 46080) reorder_one(w_adj1, Wr1, 128, 64, t - 36864);
        else if (t < 82944) stack_one(w_p16, Wt16, 256, 128, t - 46080);
        else if (t < 92160) stack_one(w_p20, Wt20, 128, 64, t - 82944);
    } else if (b < 3500) {
        int t = (b - 428) * 256 + threadIdx.x;
        if (t < 262144) pad_one(ef2, xp2, 128, 128, 128, t);
        else            pad_one(ef1, xp1, 64, 256, 256, t - 262144);
    } else {
        int c = b - 3500;
        const float* src = x + (size_t)c * 4096;
        float s = 0.f, q = 0.f;
#pragma unroll
        for (int k = 0; k < 4; k++) {
            float4 v = *(const float4*)(src + k * 1024 + threadIdx.x * 4);
            s += v.x + v.y + v.z + v.w;
            q += v.x * v.x + v.y * v.y + v.z * v.z + v.w * v.w;
        }
#pragma unroll
        for (int off = 32; off >= 1; off >>= 1) {
            s += __shfl_down(s, off, 64);
            q += __shfl_down(q, off, 64);
        }
        int wave = threadIdx.x >> 6;
        if ((threadIdx.x & 63) == 0) { ss[wave] = s; sq[wave] = q; }
        __syncthreads();
        if (threadIdx.x == 0) {
            float2 o;
            o.x = ss[0] + ss[1] + ss[2] + ss[3];
            o.y = sq[0] + sq[1] + sq[2] + sq[3];
            statX[c] = o;
        }
    }
}

// ---------------------------------------------------------------------------
// ALL-TAP conv body (shared buffers passed in; 98.7 KB total LDS, 1 blk/CU).
// ---------------------------------------------------------------------------
template <int CIN>
__device__ void conv_at_body(short* Bbuf, short* Abuf,
                             const unsigned short* __restrict__ xp,
                             const unsigned short* __restrict__ wre,
                             const float* __restrict__ bias,
                             unsigned short* __restrict__ gpl,
                             int O, int H, int W, int bx, int o0) {
    int tid = threadIdx.x;
    int lane = tid & 63, wid = tid >> 6;
    int mi = wid >> 1, ni = wid & 1;
    int l15 = lane & 15, khi = lane >> 4;
    int tpr = W >> 7;
    int y = bx / tpr;
    int x0 = (bx % tpr) << 7;
    int Wp = W + 2;
    int HW = H * W;

    floatx4 acc[4][4];
#pragma unroll
    for (int sm = 0; sm < 4; sm++)
#pragma unroll
        for (int r = 0; r < 4; r++) {
            float bv = bias[o0 + mi * 64 + sm * 16 + khi * 4 + r];
#pragma unroll
            for (int sn = 0; sn < 4; sn++) acc[sm][sn][r] = bv;
        }

    for (int cc = 0; cc < CIN / 32; cc++) {
        __syncthreads();
#pragma unroll
        for (int k = 0; k < 7; k++) {
            int s = k * 256 + tid;
            if (s < 1560) {
                int r = s >> 2, q = s & 3;
                int dy = r / 130, col = r % 130;
                const unsigned short* g =
                    xp + ((size_t)(y + dy) * Wp + x0 + col) * CIN + cc * 32 + q * 8;
                __builtin_amdgcn_global_load_lds((glb_uint*)g, (lds_uint*)(Bbuf + s * 8), 16, 0, 0);
            }
        }
#pragma unroll
        for (int k = 0; k < 18; k++) {
            int s = k * 256 + tid;
            int row = s >> 2, q = s & 3;      // row = tap*128 + m
            int tap = row >> 7, m = row & 127;
            const unsigned short* g =
                wre + ((size_t)(tap * O + o0 + m)) * CIN + cc * 32 + q * 8;
            __builtin_amdgcn_global_load_lds((glb_uint*)g, (lds_uint*)(Abuf + s * 8), 16, 0, 0);
        }
        __syncthreads();
#pragma unroll
        for (int dy = 0; dy < 3; dy++)
#pragma unroll
            for (int dx = 0; dx < 3; dx++) {
                short8 a[4], b[4];
#pragma unroll
                for (int sm = 0; sm < 4; sm++)
                    a[sm] = *(const short8*)&Abuf[((dy * 3 + dx) * 128 + mi * 64 + sm * 16 + l15) * 32 + khi * 8];
#pragma unroll
                for (int sn = 0; sn < 4; sn++)
                    b[sn] = *(const short8*)&Bbuf[(dy * 130 + ni * 64 + sn * 16 + l15 + dx) * 32 + khi * 8];
#pragma unroll
                for (int sm = 0; sm < 4; sm++)
#pragma unroll
                    for (int sn = 0; sn < 4; sn++)
                        acc[sm][sn] = __builtin_amdgcn_mfma_f32_16x16x32_bf16(
                            a[sm], b[sn], acc[sm][sn], 0, 0, 0);
            }
    }
#pragma unroll
    for (int sm = 0; sm < 4; sm++)
#pragma unroll
        for (int sn = 0; sn < 4; sn++) {
            int ob = o0 + mi * 64 + sm * 16 + khi * 4;
            int px = x0 + ni * 64 + sn * 16 + l15;
#pragma unroll
            for (int r = 0; r < 4; r++)
                gpl[(size_t)(ob + r) * HW + (size_t)y * W + px] = f2bf(acc[sm][sn][r]);
        }
}

// MERGED guide convs: blocks [0,256) = g2 (128 x-blks x 2 o-tiles),
// [256,768) = g1 (512 x-blks, single o-tile). Inputs all from K1.
__launch_bounds__(256, 1)
__global__ void conv_both_kernel(const unsigned short* __restrict__ Xp2,
                                 const unsigned short* __restrict__ Wr2,
                                 const float* __restrict__ b_adj2,
                                 unsigned short* __restrict__ Gp2,
                                 const unsigned short* __restrict__ Xp1,
                                 const unsigned short* __restrict__ Wr1,
                                 const float* __restrict__ b_adj1,
                                 unsigned short* __restrict__ Gp1) {
    __shared__ short Bbuf[390 * 32];       // 24.96 KB
    __shared__ short Abuf[9 * 128 * 32];   // 73.7 KB
    int b = blockIdx.x;
    if (b < 256) {
        int bx = b & 127, ot = b >> 7;
        conv_at_body<128>(Bbuf, Abuf, Xp2, Wr2, b_adj2, Gp2, 256, 128, 128, bx, ot << 7);
    } else {
        conv_at_body<64>(Bbuf, Abuf, Xp1, Wr1, b_adj1, Gp1, 128, 256, 256, b - 256, 0);
    }
}

// ---------------------------------------------------------------------------
// kk partial body (channel chunk of 16, planar guide). S pre-offset to chunk.
// ---------------------------------------------------------------------------
template <int CC>
__device__ __forceinline__ void kk_part_body(const unsigned short* __restrict__ g,
                                             float* __restrict__ S,
                                             int H, int W, int c0, int idx) {
    int Wh = W >> 1;
    int y = idx / Wh, xs = idx % Wh;
    int HW = H * W, HW4 = HW >> 2;
    int ys = y >> 1, ry = y & 1;
    bool xg = (xs + 1 < Wh);
    int off2 = xg ? 1 : 0;
    const unsigned short* gy = g + (size_t)y * W + 2 * xs + (size_t)c0 * HW;
    int slot = ys * Wh + xs;

    if (ry == 0) {
        float s3 = 0.f, s5 = 0.f;
        for (int c = 0; c < CC; c++) {
            const unsigned int* p = (const unsigned int*)(gy + (size_t)c * HW);
            unsigned int cc = p[0];
            unsigned int n2 = p[off2];
            float ce = bflo(cc), co = bfhi(cc);
            float d3 = ce - co;
            float d5 = bflo(n2) - co;
            s3 += d3 * d3;
            s5 += d5 * d5;
        }
        S[(size_t)3 * HW4 + slot] = s3;
        S[(size_t)4 * HW4 + slot] = 0.f;
        S[(size_t)5 * HW4 + slot] = xg ? s5 : 0.f;
    } else {
        bool yg = (y + 1 < H);
        float s0 = 0.f, s1 = 0.f, s2 = 0.f, s6 = 0.f, s7 = 0.f, s8 = 0.f;
        if (yg) {
            for (int c = 0; c < CC; c++) {
                const unsigned int* pc = (const unsigned int*)(gy + (size_t)c * HW);
                const unsigned int* pm = (const unsigned int*)(gy - W + (size_t)c * HW);
                const unsigned int* pp = (const unsigned int*)(gy + W + (size_t)c * HW);
                unsigned int cc = pc[0];
                unsigned int m0 = pm[0], m2 = pm[off2];
                unsigned int q0 = pp[0], q2 = pp[off2];
                float ce = bflo(cc), co = bfhi(cc);
                float nm = bflo(m0), np = bflo(q0);
                float d1 = nm - ce, d0 = nm - co, d2 = bflo(m2) - co;
                float d7 = np - ce, d6 = np - co, d8 = bflo(q2) - co;
                s1 += d1 * d1; s0 += d0 * d0; s2 += d2 * d2;
                s7 += d7 * d7; s6 += d6 * d6; s8 += d8 * d8;
            }
        } else {
            for (int c = 0; c < CC; c++) {
                const unsigned int* pc = (const unsigned int*)(gy + (size_t)c * HW);
                const unsigned int* pm = (const unsigned int*)(gy - W + (size_t)c * HW);
                unsigned int cc = pc[0];
                unsigned int m0 = pm[0], m2 = pm[off2];
                float ce = bflo(cc), co = bfhi(cc);
                float nm = bflo(m0);
                float d1 = nm - ce, d0 = nm - co, d2 = bflo(m2) - co;
                s1 += d1 * d1; s0 += d0 * d0; s2 += d2 * d2;
            }
        }
        S[(size_t)0 * HW4 + slot] = s0;
        S[(size_t)1 * HW4 + slot] = s1;
        S[(size_t)2 * HW4 + slot] = xg ? s2 : 0.f;
        S[(size_t)6 * HW4 + slot] = s6;
        S[(size_t)7 * HW4 + slot] = s7;
        S[(size_t)8 * HW4 + slot] = (xg && yg) ? s8 : 0.f;
    }
}

// ---------------------------------------------------------------------------
// MERGED: kk2 [0,512) + kk1 [512,1536) + stage-0 transpose [1536,2048).
// ---------------------------------------------------------------------------
__global__ void kk_both_transpose_kernel(const unsigned short* __restrict__ Gp2,
                                         float* __restrict__ Sp2,
                                         const unsigned short* __restrict__ Gp1,
                                         float* __restrict__ Sp1,
                                         const float* __restrict__ x,
                                         const float2* __restrict__ statX,
                                         unsigned short* __restrict__ Xt16) {
    int b = blockIdx.x;
    if (b < 512) {
        int chunk = b >> 5, xblk = b & 31;
        kk_part_body<16>(Gp2, Sp2 + (size_t)chunk * 9 * 4096, 128, 128,
                         chunk * 16, xblk * 256 + (int)threadIdx.x);
    } else if (b < 1536) {
        b -= 512;
        int chunk = b >> 7, xblk = b & 127;
        kk_part_body<16>(Gp1, Sp1 + (size_t)chunk * 9 * 16384, 256, 256,
                         chunk * 16, xblk * 256 + (int)threadIdx.x);
    } else {
        int t = (b - 1536) * 256 + threadIdx.x;
        int p = t % 4096;
        int cg = t / 4096;
        float Av[8], Bv[8];
#pragma unroll
        for (int i = 0; i < 8; i++) {
            float2 pp = statX[cg * 8 + i];
            composed_norm(pp.x, pp.y, 4096.f, Av[i], Bv[i]);
        }
        ushort8 v;
#pragma unroll
        for (int i = 0; i < 8; i++) {
            float xv = x[(size_t)(cg * 8 + i) * 4096 + p];
            v[i] = f2bf(fmaf(xv, Av[i], Bv[i]));
        }
        *(ushort8*)&Xt16[(size_t)p * 256 + cg * 8] = v;
    }
}

// ---------------------------------------------------------------------------
// GEMM body (K-contig bf16 A[M][K] x B[N][K] -> bf16 P[M][N]).
// ---------------------------------------------------------------------------
template <int K>
__device__ void gemm_bt_body(const unsigned short* __restrict__ A,
                             const unsigned short* __restrict__ B,
                             unsigned short* __restrict__ P, int N,
                             int m0, int n0) {
    __shared__ short Ab[128 * 32];
    __shared__ short Bb[128 * 32];
    int tid = threadIdx.x;
    int lane = tid & 63, wid = tid >> 6;
    int mi = wid >> 1, ni = wid & 1;
    int l15 = lane & 15, khi = lane >> 4;

    floatx4 acc[4][4];
#pragma unroll
    for (int sm = 0; sm < 4; sm++)
#pragma unroll
        for (int sn = 0; sn < 4; sn++)
#pragma unroll
            for (int r = 0; r < 4; r++) acc[sm][sn][r] = 0.f;

    for (int kc = 0; kc < K / 32; kc++) {
        __syncthreads();
#pragma unroll
        for (int k = 0; k < 2; k++) {
            int s = k * 256 + tid;
            int row = s >> 2, q = s & 3;
            const unsigned short* ga = A + (size_t)(m0 + row) * K + kc * 32 + q * 8;
            __builtin_amdgcn_global_load_lds((glb_uint*)ga, (lds_uint*)(Ab + s * 8), 16, 0, 0);
            const unsigned short* gb = B + (size_t)(n0 + row) * K + kc * 32 + q * 8;
            __builtin_amdgcn_global_load_lds((glb_uint*)gb, (lds_uint*)(Bb + s * 8), 16, 0, 0);
        }
        __syncthreads();
        short8 a[4], b[4];
#pragma unroll
        for (int sm = 0; sm < 4; sm++)
            a[sm] = *(const short8*)&Ab[(mi * 64 + sm * 16 + l15) * 32 + khi * 8];
#pragma unroll
        for (int sn = 0; sn < 4; sn++)
            b[sn] = *(const short8*)&Bb[(ni * 64 + sn * 16 + l15) * 32 + khi * 8];
#pragma unroll
        for (int sm = 0; sm < 4; sm++)
#pragma unroll
            for (int sn = 0; sn < 4; sn++)
                acc[sm][sn] = __builtin_amdgcn_mfma_f32_16x16x32_bf16(
                    a[sm], b[sn], acc[sm][sn], 0, 0, 0);
    }
#pragma unroll
    for (int sm = 0; sm < 4; sm++)
#pragma unroll
        for (int sn = 0; sn < 4; sn++) {
            int m = m0 + mi * 64 + sm * 16 + khi * 4;
            int n = n0 + ni * 64 + sn * 16 + l15;
#pragma unroll
            for (int r = 0; r < 4; r++)
                P[(size_t)(m + r) * N + n] = f2bf(acc[sm][sn][r]);
        }
}

// MERGED: gemm16 [0,288) + Sp2 reduce [288,432) + Sp1 reduce [432,1008).
__launch_bounds__(256, 3)
__global__ void gemm16_red_kernel(const unsigned short* __restrict__ Wt16,
                                  const unsigned short* __restrict__ Xt16,
                                  unsigned short* __restrict__ P16,
                                  const float* __restrict__ Sp2, float* __restrict__ Sf2,
                                  const float* __restrict__ Sp1, float* __restrict__ Sf1) {
    int b = blockIdx.x;
    if (b < 288) {
        int n0 = (b & 31) << 7;
        int m0 = (b >> 5) << 7;
        gemm_bt_body<256>(Wt16, Xt16, P16, 4096, m0, n0);
    } else if (b < 432) {
        int i = (b - 288) * 256 + threadIdx.x;
        if (i < 36864) {
            float s = 0.f;
            for (int ch = 0; ch < 16; ch++) s += Sp2[(size_t)ch * 36864 + i];
            Sf2[i] = s;
        }
    } else {
        int i = (b - 432) * 256 + threadIdx.x;
        if (i < 147456) {
            float s = 0.f;
            for (int ch = 0; ch < 8; ch++) s += Sp1[(size_t)ch * 147456 + i];
            Sf1[i] = s;
        }
    }
}

// Plain gemm kernel for pac20.
template <int K>
__launch_bounds__(256, 3)
__global__ void gemm_bt_kernel(const unsigned short* __restrict__ A,
                               const unsigned short* __restrict__ B,
                               unsigned short* __restrict__ P, int N) {
    gemm_bt_body<K>(A, B, P, N, blockIdx.y << 7, blockIdx.x << 7);
}

// ---------------------------------------------------------------------------
// Fused DOUBLE instance-norm + transpose, planar-bf16 input (stage 1).
// ---------------------------------------------------------------------------
__global__ void transpose_norm2_bf16_kernel(const unsigned short* __restrict__ in,
                                            const float2* __restrict__ parts, int NB,
                                            unsigned short* __restrict__ xt,
                                            int C, int HW) {
    int t = blockIdx.x * blockDim.x + threadIdx.x;
    int p = t % HW;
    int cg = t / HW;
    float Av[8], Bv[8];
#pragma unroll
    for (int i = 0; i < 8; i++) {
        int c = cg * 8 + i;
        float s = 0.f, q = 0.f;
        for (int nb = 0; nb < NB; nb++) {
            float2 pp = parts[c * NB + nb];
            s += pp.x; q += pp.y;
        }
        composed_norm(s, q, (float)HW, Av[i], Bv[i]);
    }
    ushort8 v;
#pragma unroll
    for (int i = 0; i < 8; i++) {
        float x = bf2f(in[(size_t)(cg * 8 + i) * HW + p]);
        v[i] = f2bf(fmaf(x, Av[i], Bv[i]));
    }
    *(ushort8*)&xt[(size_t)p * C + cg * 8] = v;
}

// ---------------------------------------------------------------------------
// PAC combine, parity-pair form; planar bf16 out + raw stats partials.
// ---------------------------------------------------------------------------
__global__ void pac_combine2_kernel(const unsigned short* __restrict__ P,
                                    const float* __restrict__ S,
                                    const float* __restrict__ bias,
                                    unsigned short* __restrict__ out,
                                    float2* __restrict__ statOut,
                                    int O, int Hi, int Wi) {
    int HW4 = Hi * Wi;
    int Wo = Wi * 2;
    int HoWo = 4 * HW4;
    int idx = blockIdx.x * blockDim.x + threadIdx.x;
    int pixh = idx % HW4;
    int og = idx / HW4;
    int ys = pixh / Wi, xs = pixh % Wi;
    int ry = blockIdx.z;
    int y = 2 * ys + ry;
    bool xg = (xs + 1 < Wi);
    bool yg = (ys + 1 < Hi);
    size_t rowb = (size_t)ys * Wi + xs;

    float ev[4], ov[4];

    if (ry == 0) {
        float k3 = __expf(-0.5f * S[(size_t)3 * HW4 + pixh]);
        float k4 = __expf(-0.5f * S[(size_t)4 * HW4 + pixh]);
        float k5 = __expf(-0.5f * S[(size_t)5 * HW4 + pixh]);
#pragma unroll
        for (int r = 0; r < 4; r++) {
            int o = og * 4 + r;
            float bv = bias[o];
            const unsigned short* p3 = P + (size_t)(3 * O + o) * HW4 + rowb;
            const unsigned short* p4 = P + (size_t)(4 * O + o) * HW4 + rowb;
            const unsigned short* p5 = P + (size_t)(5 * O + o) * HW4 + rowb;
            float v4 = bf2f(p4[0]);
            float v3 = bf2f(p3[0]);
            float v5 = xg ? bf2f(p5[1]) : 0.f;
            ev[r] = bv + k4 * v4;
            ov[r] = bv + k3 * v3 + k5 * v5;
        }
    } else {
        float k0 = __expf(-0.5f * S[(size_t)0 * HW4 + pixh]);
        float k1 = __expf(-0.5f * S[(size_t)1 * HW4 + pixh]);
        float k2 = __expf(-0.5f * S[(size_t)2 * HW4 + pixh]);
        float k6 = __expf(-0.5f * S[(size_t)6 * HW4 + pixh]);
        float k7 = __expf(-0.5f * S[(size_t)7 * HW4 + pixh]);
        float k8 = __expf(-0.5f * S[(size_t)8 * HW4 + pixh]);
#pragma unroll
        for (int r = 0; r < 4; r++) {
            int o = og * 4 + r;
            float bv = bias[o];
            const unsigned short* p0 = P + (size_t)(0 * O + o) * HW4 + rowb;
            const unsigned short* p1 = P + (size_t)(1 * O + o) * HW4 + rowb;
            const unsigned short* p2 = P + (size_t)(2 * O + o) * HW4 + rowb;
            const unsigned short* p6 = P + (size_t)(6 * O + o) * HW4 + rowb + Wi;
            const unsigned short* p7 = P + (size_t)(7 * O + o) * HW4 + rowb + Wi;
            const unsigned short* p8 = P + (size_t)(8 * O + o) * HW4 + rowb + Wi;
            float v1 = bf2f(p1[0]);
            float v0 = bf2f(p0[0]);
            float v2 = xg ? bf2f(p2[1]) : 0.f;
            float v7 = yg ? bf2f(p7[0]) : 0.f;
            float v6 = yg ? bf2f(p6[0]) : 0.f;
            float v8 = (yg && xg) ? bf2f(p8[1]) : 0.f;
            ev[r] = bv + k1 * v1 + k7 * v7;
            ov[r] = bv + k0 * v0 + k2 * v2 + k6 * v6 + k8 * v8;
        }
    }
#pragma unroll
    for (int r = 0; r < 4; r++) {
        unsigned int pk = (unsigned int)f2bf(ev[r]) | ((unsigned int)f2bf(ov[r]) << 16);
        *(unsigned int*)&out[(size_t)(og * 4 + r) * HoWo + (size_t)y * Wo + 2 * xs] = pk;
    }

    __shared__ float rs[4][4], rq[4][4];
    int wave = threadIdx.x >> 6;
#pragma unroll
    for (int r = 0; r < 4; r++) {
        float s = ev[r] + ov[r];
        float q = ev[r] * ev[r] + ov[r] * ov[r];
#pragma unroll
        for (int off = 32; off >= 1; off >>= 1) {
            s += __shfl_down(s, off, 64);
            q += __shfl_down(q, off, 64);
        }
        if ((threadIdx.x & 63) == 0) { rs[wave][r] = s; rq[wave][r] = q; }
    }
    __syncthreads();
    if (threadIdx.x < 4) {
        int r = threadIdx.x;
        float s = rs[0][r] + rs[1][r] + rs[2][r] + rs[3][r];
        float q = rq[0][r] + rq[1][r] + rq[2][r] + rq[3][r];
        atomicAdd(&statOut[og * 4 + r].x, s);
        atomicAdd(&statOut[og * 4 + r].y, q);
    }
}

// ---------------------------------------------------------------------------
// Final conv with fused composed DOUBLE norm, planar-bf16 input.
// ---------------------------------------------------------------------------
__global__ void conv_part_norm_kernel(const unsigned short* __restrict__ in,
                                      const float* __restrict__ w,
                                      const float2* __restrict__ parts, int NB,
                                      float* __restrict__ Pf, int H, int W) {
    __shared__ float wsm[16 * 9 * 3];
    __shared__ float am[16], bm[16];
    int q0 = blockIdx.y * 16;
    int HW = H * W;
    for (int t = threadIdx.x; t < 432; t += blockDim.x) {
        int oc = t % 3;
        int tap = (t / 3) % 9;
        int c = t / 27;
        wsm[t] = w[((size_t)oc * 64 + q0 + c) * 9 + tap];
    }
    if (threadIdx.x < 16) {
        int c = q0 + threadIdx.x;
        float s = 0.f, q = 0.f;
        for (int nb = 0; nb < NB; nb++) {
            float2 pp = parts[c * NB + nb];
            s += pp.x; q += pp.y;
        }
        float A, B;
        composed_norm(s, q, (float)HW, A, B);
        am[threadIdx.x] = A;
        bm[threadIdx.x] = B;
    }
    __syncthreads();
    int pix = blockIdx.x * blockDim.x + threadIdx.x;
    int y = pix / W, x = pix % W;
    float acc[3] = {0.f, 0.f, 0.f};
    bool xl = (x > 0), xr = (x < W - 1);
    for (int c = 0; c < 16; c++) {
        const unsigned short* base = in + (size_t)(q0 + c) * HW + pix;
        const float* wc = wsm + c * 27;
        float ac = am[c], bc = bm[c];
#pragma unroll
        for (int dy = 0; dy < 3; dy++) {
            int yy = y + dy - 1;
            if (yy < 0 || yy >= H) continue;
            const unsigned short* row = base + (dy - 1) * W;
            float v0 = xl ? fmaf(bf2f(row[-1]), ac, bc) : 0.f;
            float v1 = fmaf(bf2f(row[0]), ac, bc);
            float v2 = xr ? fmaf(bf2f(row[1]), ac, bc) : 0.f;
#pragma unroll
            for (int ob = 0; ob < 3; ob++) {
                acc[ob] += v0 * wc[(dy * 3 + 0) * 3 + ob];
                acc[ob] += v1 * wc[(dy * 3 + 1) * 3 + ob];
                acc[ob] += v2 * wc[(dy * 3 + 2) * 3 + ob];
            }
        }
    }
#pragma unroll
    for (int ob = 0; ob < 3; ob++)
        Pf[(size_t)(blockIdx.y * 3 + ob) * HW + pix] = acc[ob];
}

__global__ void conv_fin_kernel(const float* __restrict__ Pf, const float* __restrict__ bias,
                                float* __restrict__ out, int HW) {
    int pix = blockIdx.x * blockDim.x + threadIdx.x;
#pragma unroll
    for (int ob = 0; ob < 3; ob++) {
        float a = bias[ob];
#pragma unroll
        for (int q = 0; q < 4; q++)
            a += Pf[(size_t)(q * 3 + ob) * HW + pix];
        out[(size_t)ob * HW + pix] = a;
    }
}

// ---------------------------------------------------------------------------
extern "C" void kernel_launch(void* const* d_in, const int* in_sizes, int n_in,
                              void* d_out, int out_size, void* d_ws, size_t ws_size,
                              hipStream_t stream) {
    const float* x      = (const float*)d_in[0];   // (256,64,64)
    const float* ef2    = (const float*)d_in[1];   // (128,128,128)
    const float* ef1    = (const float*)d_in[2];   // (64,256,256)
    const float* w_adj2 = (const float*)d_in[3];
    const float* b_adj2 = (const float*)d_in[4];
    const float* w_adj1 = (const float*)d_in[5];
    const float* b_adj1 = (const float*)d_in[6];
    const float* w_p16  = (const float*)d_in[7];
    const float* b_p16  = (const float*)d_in[8];
    const float* w_p20  = (const float*)d_in[9];
    const float* b_p20  = (const float*)d_in[10];
    const float* w_out  = (const float*)d_in[11];
    const float* b_out  = (const float*)d_in[12];
    float* out = (float*)d_out;                    // (3,256,256)

    // ---- workspace layout (float offsets) ----
    float* ws = (float*)d_ws;
    unsigned short* bxb1 = (unsigned short*)(ws + 1048576);   // bf16
    unsigned short* bxb2 = (unsigned short*)(ws + 3145728);   // bf16
    unsigned short* Wt16 = (unsigned short*)(ws + 5242880);
    unsigned short* Xt16 = (unsigned short*)(ws + 5390336);
    float* bk2c = ws + 7340032;
    float* bk1c = ws + 7376896;
    float2* statX   = (float2*)(ws + 7524352);
    float2* statP16 = (float2*)(ws + 7525376);
    float2* statP20 = (float2*)(ws + 7526656);
    unsigned short* Wt20 = (unsigned short*)(ws + 7528832);
    unsigned short* Gp1  = (unsigned short*)(ws + 7569792);
    unsigned short* P16  = (unsigned short*)(ws + 7569792);
    unsigned short* P20  = (unsigned short*)(ws + 7569792);
    unsigned short* Gp2  = (unsigned short*)(ws + 12812672);
    unsigned short* Xt20 = (unsigned short*)(ws + 12812672);
    unsigned short* Xp2 = (unsigned short*)(ws + 14975872);
    unsigned short* Wr2 = (unsigned short*)(ws + 16057472);
    unsigned short* Xp1 = (unsigned short*)(ws + 16204928);
    unsigned short* Wr1 = (unsigned short*)(ws + 18334976);
    float* Pf = ws + 14975872;
    float* Sp2 = ws + 18371840;
    float* Sp1 = ws + 18961664;

    // K1: PROLOGUE
    prologue_kernel<<<3756, 256, 0, stream>>>(
        (uint4v*)(ws + 7525376), Xp2, Xp1,
        w_adj2, Wr2, w_adj1, Wr1, w_p16, Wt16, w_p20, Wt20,
        ef2, ef1, x, statX);

    // K2: both guide convs (all-tap, merged: 256 g2-blocks + 512 g1-blocks)
    conv_both_kernel<<<768, 256, 0, stream>>>(Xp2, Wr2, b_adj2, Gp2,
                                              Xp1, Wr1, b_adj1, Gp1);

    // K3: kk2 + kk1 + stage-0 transpose
    kk_both_transpose_kernel<<<2048, 256, 0, stream>>>(Gp2, Sp2, Gp1, Sp1, x, statX, Xt16);

    // K4: gemm16 + Sp2 reduce + Sp1 reduce
    gemm16_red_kernel<<<1008, 256, 0, stream>>>(Wt16, Xt16, P16, Sp2, bk2c, Sp1, bk1c);

    // K5: combine16 -> bxb1 + statP16
    pac_combine2_kernel<<<dim3(512, 1, 2), 256, 0, stream>>>(P16, bk2c, b_p16, bxb1, statP16, 128, 64, 64);

    // K6: stage-1 double-norm transpose (bf16 in)
    transpose_norm2_bf16_kernel<<<1024, 256, 0, stream>>>(bxb1, statP16, 1, Xt20, 128, 16384);

    // K7: gemm20
    gemm_bt_kernel<128><<<dim3(128, 5), 256, 0, stream>>>(Wt20, Xt20, P20, 16384);

    // K8: combine20 -> bxb2 + statP20
    pac_combine2_kernel<<<dim3(1024, 1, 2), 256, 0, stream>>>(P20, bk1c, b_p20, bxb2, statP20, 64, 128, 128);

    // K9/K10: final conv (norm fused) + sum
    conv_part_norm_kernel<<<dim3(256, 4), 256, 0, stream>>>(bxb2, w_out, statP20, 1, Pf, 256, 256);
    conv_fin_kernel<<<256, 256, 0, stream>>>(Pf, b_out, out, 65536);
}

// Round 20
// 227.013 us; speedup vs baseline: 1.0303x; 1.0303x over previous
//
#include <hip/hip_runtime.h>
#include <hip/hip_bf16.h>
#include <cstdint>
#include <cstddef>

#define EPS_IN 1e-5f

typedef __attribute__((ext_vector_type(8))) short short8;
typedef __attribute__((ext_vector_type(4))) float floatx4;
typedef __attribute__((ext_vector_type(8))) unsigned short ushort8;
typedef __attribute__((ext_vector_type(4))) unsigned int uint4v;
typedef __attribute__((address_space(3))) unsigned int lds_uint;
typedef __attribute__((address_space(1))) const unsigned int glb_uint;

__device__ __forceinline__ unsigned short f2bf(float f) {
    unsigned int u = __float_as_uint(f);
    u += 0x7FFFu + ((u >> 16) & 1u);     // RNE
    return (unsigned short)(u >> 16);
}
__device__ __forceinline__ float bf2f(unsigned short s) {
    return __uint_as_float((unsigned int)s << 16);
}
__device__ __forceinline__ float bflo(unsigned int u) {
    return __uint_as_float(u << 16);
}
__device__ __forceinline__ float bfhi(unsigned int u) {
    return __uint_as_float(u & 0xFFFF0000u);
}

// Composed double instance-norm affine from raw (sum, sumsq).
__device__ __forceinline__ void composed_norm(float s, float q, float HW,
                                              float& A, float& B) {
    float m1 = s / HW;
    float v1 = q / HW - m1 * m1;
    float r1 = rsqrtf(v1 + EPS_IN);
    float a1 = 1.f + r1;
    float b1 = -m1 * r1;
    float r2 = rsqrtf(a1 * a1 * v1 + EPS_IN);
    float a2 = 1.f + r2;
    A = a1 * a2;
    B = a2 * b1 - m1 * r2;
}

// ---------------------------------------------------------------------------
// prologue helpers
// ---------------------------------------------------------------------------
__device__ __forceinline__ void border_zero(unsigned short* buf, int C, int H, int W, int idx) {
    int Hp = H + 2, Wp = W + 2;
    int cg8 = C >> 3;
    int cg = idx % cg8;
    int bi = idx / cg8;
    int y, x;
    if (bi < Wp) { y = 0; x = bi; }
    else if (bi < 2 * Wp) { y = Hp - 1; x = bi - Wp; }
    else {
        int k = bi - 2 * Wp;
        y = 1 + (k >> 1);
        x = (k & 1) ? (Wp - 1) : 0;
    }
    ushort8 z = {0, 0, 0, 0, 0, 0, 0, 0};
    *(ushort8*)&buf[((size_t)y * Wp + x) * C + cg * 8] = z;
}

__device__ __forceinline__ void reorder_one(const float* w, unsigned short* dst,
                                            int O, int C, int j) {
    int cg8 = C >> 3;
    int cg = j % cg8;
    int o = (j / cg8) % O;
    int tap = j / (cg8 * O);
    ushort8 v;
#pragma unroll
    for (int i = 0; i < 8; i++)
        v[i] = f2bf(w[((size_t)o * C + cg * 8 + i) * 9 + tap]);
    *(ushort8*)&dst[((size_t)tap * O + o) * C + cg * 8] = v;
}
__device__ __forceinline__ void stack_one(const float* w, unsigned short* dst,
                                          int C, int O, int j) {
    int cg8 = C >> 3;
    int cg = j % cg8;
    int o = (j / cg8) % O;
    int tap = j / (cg8 * O);
    ushort8 v;
#pragma unroll
    for (int i = 0; i < 8; i++)
        v[i] = f2bf(w[((size_t)(cg * 8 + i) * O + o) * 9 + tap]);
    *(ushort8*)&dst[((size_t)tap * O + o) * C + cg * 8] = v;
}

__device__ __forceinline__ void pad_one(const float* in, unsigned short* xp,
                                        int C, int H, int W, int t) {
    int HW = H * W;
    int p = t % HW;
    int cg = t / HW;
    int y = p / W, x = p % W;
    ushort8 v;
#pragma unroll
    for (int i = 0; i < 8; i++)
        v[i] = f2bf(in[(size_t)(cg * 8 + i) * HW + p]);
    *(ushort8*)&xp[((size_t)(y + 1) * (W + 2) + (x + 1)) * C + cg * 8] = v;
}

// ---------------------------------------------------------------------------
// PROLOGUE mega-kernel (r16-proven).
// ---------------------------------------------------------------------------
__global__ void prologue_kernel(uint4v* __restrict__ statz,
                                unsigned short* __restrict__ xp2,
                                unsigned short* __restrict__ xp1,
                                const float* __restrict__ w_adj2, unsigned short* __restrict__ Wr2,
                                const float* __restrict__ w_adj1, unsigned short* __restrict__ Wr1,
                                const float* __restrict__ w_p16, unsigned short* __restrict__ Wt16,
                                const float* __restrict__ w_p20, unsigned short* __restrict__ Wt20,
                                const float* __restrict__ ef2, const float* __restrict__ ef1,
                                const float* __restrict__ x, float2* __restrict__ statX) {
    __shared__ float ss[4], sq[4];
    int b = blockIdx.x;
    if (b < 68) {
        int t = b * 256 + threadIdx.x;
        const int NZ = 864;
        const int N2 = 516 * 16;
        const int N1 = 1028 * 8;
        if (t < NZ) {
            uint4v z = {0u, 0u, 0u, 0u};
            statz[t] = z;
        } else if (t < NZ + N2) {
            border_zero(xp2, 128, 128, 128, t - NZ);
        } else if (t < NZ + N2 + N1) {
            border_zero(xp1, 64, 256, 256, t - NZ - N2);
        }
    } else if (b < 428) {
        int t = (b - 68) * 256 + threadIdx.x;
        if (t < 36864) reorder_one(w_adj2, Wr2, 256, 128, t);
        else if (t < 46080) reorder_one(w_adj1, Wr1, 128, 64, t - 36864);
        else if (t < 82944) stack_one(w_p16, Wt16, 256, 128, t - 46080);
        else if (t < 92160) stack_one(w_p20, Wt20, 128, 64, t - 82944);
    } else if (b < 3500) {
        int t = (b - 428) * 256 + threadIdx.x;
        if (t < 262144) pad_one(ef2, xp2, 128, 128, 128, t);
        else            pad_one(ef1, xp1, 64, 256, 256, t - 262144);
    } else {
        int c = b - 3500;
        const float* src = x + (size_t)c * 4096;
        float s = 0.f, q = 0.f;
#pragma unroll
        for (int k = 0; k < 4; k++) {
            float4 v = *(const float4*)(src + k * 1024 + threadIdx.x * 4);
            s += v.x + v.y + v.z + v.w;
            q += v.x * v.x + v.y * v.y + v.z * v.z + v.w * v.w;
        }
#pragma unroll
        for (int off = 32; off >= 1; off >>= 1) {
            s += __shfl_down(s, off, 64);
            q += __shfl_down(q, off, 64);
        }
        int wave = threadIdx.x >> 6;
        if ((threadIdx.x & 63) == 0) { ss[wave] = s; sq[wave] = q; }
        __syncthreads();
        if (threadIdx.x == 0) {
            float2 o;
            o.x = ss[0] + ss[1] + ss[2] + ss[3];
            o.y = sq[0] + sq[1] + sq[2] + sq[3];
            statX[c] = o;
        }
    }
}

// ---------------------------------------------------------------------------
// ALL-TAP conv body, 2-ROW tile: block = 2 output rows x 128 cols x 128 o.
// B tile = 4 input rows x 130 cols x 32 ch (33.3 KB); A = 9 taps x 128 o x
// 32 ch (73.7 KB). Wave (mi,ni): 64 o x (row y0+ni, 128 cols) -> acc[4][8].
// Per (dy,dx): 12 ds_read_b128 -> 32 MFMA (vs 8 -> 16 in the 1-row tile);
// A-restaging per output pixel halved.
// ---------------------------------------------------------------------------
template <int CIN>
__device__ void conv_at2_body(short* Bbuf, short* Abuf,
                              const unsigned short* __restrict__ xp,
                              const unsigned short* __restrict__ wre,
                              const float* __restrict__ bias,
                              unsigned short* __restrict__ gpl,
                              int O, int H, int W, int y0, int x0, int o0) {
    int tid = threadIdx.x;
    int lane = tid & 63, wid = tid >> 6;
    int mi = wid >> 1, ni = wid & 1;
    int l15 = lane & 15, khi = lane >> 4;
    int Wp = W + 2;
    int HW = H * W;

    floatx4 acc[4][8];
#pragma unroll
    for (int sm = 0; sm < 4; sm++)
#pragma unroll
        for (int r = 0; r < 4; r++) {
            float bv = bias[o0 + mi * 64 + sm * 16 + khi * 4 + r];
#pragma unroll
            for (int sn = 0; sn < 8; sn++) acc[sm][sn][r] = bv;
        }

    for (int cc = 0; cc < CIN / 32; cc++) {
        __syncthreads();                   // prior reads of A/B done
        // stage B: 4 rows x 130 cols -> 520*4 = 2080 16B slots
#pragma unroll
        for (int k = 0; k < 9; k++) {
            int s = k * 256 + tid;
            if (s < 2080) {
                int r = s >> 2, q = s & 3;
                int dyr = r / 130, col = r % 130;
                const unsigned short* g =
                    xp + ((size_t)(y0 + dyr) * Wp + x0 + col) * CIN + cc * 32 + q * 8;
                __builtin_amdgcn_global_load_lds((glb_uint*)g, (lds_uint*)(Bbuf + s * 8), 16, 0, 0);
            }
        }
        // stage A, all 9 taps: 4608 slots (exact 18/thread)
#pragma unroll
        for (int k = 0; k < 18; k++) {
            int s = k * 256 + tid;
            int row = s >> 2, q = s & 3;      // row = tap*128 + m
            int tap = row >> 7, m = row & 127;
            const unsigned short* g =
                wre + ((size_t)(tap * O + o0 + m)) * CIN + cc * 32 + q * 8;
            __builtin_amdgcn_global_load_lds((glb_uint*)g, (lds_uint*)(Abuf + s * 8), 16, 0, 0);
        }
        __syncthreads();                   // A+B visible
#pragma unroll
        for (int dy = 0; dy < 3; dy++)
#pragma unroll
            for (int dx = 0; dx < 3; dx++) {
                short8 a[4], b[8];
#pragma unroll
                for (int sm = 0; sm < 4; sm++)
                    a[sm] = *(const short8*)&Abuf[((dy * 3 + dx) * 128 + mi * 64 + sm * 16 + l15) * 32 + khi * 8];
#pragma unroll
                for (int sn = 0; sn < 8; sn++)
                    b[sn] = *(const short8*)&Bbuf[((ni + dy) * 130 + sn * 16 + l15 + dx) * 32 + khi * 8];
#pragma unroll
                for (int sm = 0; sm < 4; sm++)
#pragma unroll
                    for (int sn = 0; sn < 8; sn++)
                        acc[sm][sn] = __builtin_amdgcn_mfma_f32_16x16x32_bf16(
                            a[sm], b[sn], acc[sm][sn], 0, 0, 0);
            }
    }
#pragma unroll
    for (int sm = 0; sm < 4; sm++)
#pragma unroll
        for (int sn = 0; sn < 8; sn++) {
            int ob = o0 + mi * 64 + sm * 16 + khi * 4;
            int px = x0 + sn * 16 + l15;
#pragma unroll
            for (int r = 0; r < 4; r++)
                gpl[(size_t)(ob + r) * HW + (size_t)(y0 + ni) * W + px] = f2bf(acc[sm][sn][r]);
        }
}

// MERGED guide convs, 2-row tiles: blocks [0,128) = g2 (64 row-pairs x 2
// o-tiles), [128,384) = g1 (128 row-pairs x 2 x-tiles).
__launch_bounds__(256, 1)
__global__ void conv_both_kernel(const unsigned short* __restrict__ Xp2,
                                 const unsigned short* __restrict__ Wr2,
                                 const float* __restrict__ b_adj2,
                                 unsigned short* __restrict__ Gp2,
                                 const unsigned short* __restrict__ Xp1,
                                 const unsigned short* __restrict__ Wr1,
                                 const float* __restrict__ b_adj1,
                                 unsigned short* __restrict__ Gp1) {
    __shared__ short Bbuf[4 * 130 * 32];   // 33.3 KB
    __shared__ short Abuf[9 * 128 * 32];   // 73.7 KB
    int b = blockIdx.x;
    if (b < 128) {
        int yp = b & 63, ot = b >> 6;
        conv_at2_body<128>(Bbuf, Abuf, Xp2, Wr2, b_adj2, Gp2, 256, 128, 128,
                           2 * yp, 0, ot << 7);
    } else {
        int bb = b - 128;
        int yp = bb >> 1, xt = bb & 1;
        conv_at2_body<64>(Bbuf, Abuf, Xp1, Wr1, b_adj1, Gp1, 128, 256, 256,
                          2 * yp, xt << 7, 0);
    }
}

// ---------------------------------------------------------------------------
// kk partial body (channel chunk of 16, planar guide). S pre-offset to chunk.
// ---------------------------------------------------------------------------
template <int CC>
__device__ __forceinline__ void kk_part_body(const unsigned short* __restrict__ g,
                                             float* __restrict__ S,
                                             int H, int W, int c0, int idx) {
    int Wh = W >> 1;
    int y = idx / Wh, xs = idx % Wh;
    int HW = H * W, HW4 = HW >> 2;
    int ys = y >> 1, ry = y & 1;
    bool xg = (xs + 1 < Wh);
    int off2 = xg ? 1 : 0;
    const unsigned short* gy = g + (size_t)y * W + 2 * xs + (size_t)c0 * HW;
    int slot = ys * Wh + xs;

    if (ry == 0) {
        float s3 = 0.f, s5 = 0.f;
        for (int c = 0; c < CC; c++) {
            const unsigned int* p = (const unsigned int*)(gy + (size_t)c * HW);
            unsigned int cc = p[0];
            unsigned int n2 = p[off2];
            float ce = bflo(cc), co = bfhi(cc);
            float d3 = ce - co;
            float d5 = bflo(n2) - co;
            s3 += d3 * d3;
            s5 += d5 * d5;
        }
        S[(size_t)3 * HW4 + slot] = s3;
        S[(size_t)4 * HW4 + slot] = 0.f;
        S[(size_t)5 * HW4 + slot] = xg ? s5 : 0.f;
    } else {
        bool yg = (y + 1 < H);
        float s0 = 0.f, s1 = 0.f, s2 = 0.f, s6 = 0.f, s7 = 0.f, s8 = 0.f;
        if (yg) {
            for (int c = 0; c < CC; c++) {
                const unsigned int* pc = (const unsigned int*)(gy + (size_t)c * HW);
                const unsigned int* pm = (const unsigned int*)(gy - W + (size_t)c * HW);
                const unsigned int* pp = (const unsigned int*)(gy + W + (size_t)c * HW);
                unsigned int cc = pc[0];
                unsigned int m0 = pm[0], m2 = pm[off2];
                unsigned int q0 = pp[0], q2 = pp[off2];
                float ce = bflo(cc), co = bfhi(cc);
                float nm = bflo(m0), np = bflo(q0);
                float d1 = nm - ce, d0 = nm - co, d2 = bflo(m2) - co;
                float d7 = np - ce, d6 = np - co, d8 = bflo(q2) - co;
                s1 += d1 * d1; s0 += d0 * d0; s2 += d2 * d2;
                s7 += d7 * d7; s6 += d6 * d6; s8 += d8 * d8;
            }
        } else {
            for (int c = 0; c < CC; c++) {
                const unsigned int* pc = (const unsigned int*)(gy + (size_t)c * HW);
                const unsigned int* pm = (const unsigned int*)(gy - W + (size_t)c * HW);
                unsigned int cc = pc[0];
                unsigned int m0 = pm[0], m2 = pm[off2];
                float ce = bflo(cc), co = bfhi(cc);
                float nm = bflo(m0);
                float d1 = nm - ce, d0 = nm - co, d2 = bflo(m2) - co;
                s1 += d1 * d1; s0 += d0 * d0; s2 += d2 * d2;
            }
        }
        S[(size_t)0 * HW4 + slot] = s0;
        S[(size_t)1 * HW4 + slot] = s1;
        S[(size_t)2 * HW4 + slot] = xg ? s2 : 0.f;
        S[(size_t)6 * HW4 + slot] = s6;
        S[(size_t)7 * HW4 + slot] = s7;
        S[(size_t)8 * HW4 + slot] = (xg && yg) ? s8 : 0.f;
    }
}

// ---------------------------------------------------------------------------
// MERGED: kk2 [0,512) + kk1 [512,1536) + stage-0 transpose [1536,2048).
// ---------------------------------------------------------------------------
__global__ void kk_both_transpose_kernel(const unsigned short* __restrict__ Gp2,
                                         float* __restrict__ Sp2,
                                         const unsigned short* __restrict__ Gp1,
                                         float* __restrict__ Sp1,
                                         const float* __restrict__ x,
                                         const float2* __restrict__ statX,
                                         unsigned short* __restrict__ Xt16) {
    int b = blockIdx.x;
    if (b < 512) {
        int chunk = b >> 5, xblk = b & 31;
        kk_part_body<16>(Gp2, Sp2 + (size_t)chunk * 9 * 4096, 128, 128,
                         chunk * 16, xblk * 256 + (int)threadIdx.x);
    } else if (b < 1536) {
        b -= 512;
        int chunk = b >> 7, xblk = b & 127;
        kk_part_body<16>(Gp1, Sp1 + (size_t)chunk * 9 * 16384, 256, 256,
                         chunk * 16, xblk * 256 + (int)threadIdx.x);
    } else {
        int t = (b - 1536) * 256 + threadIdx.x;
        int p = t % 4096;
        int cg = t / 4096;
        float Av[8], Bv[8];
#pragma unroll
        for (int i = 0; i < 8; i++) {
            float2 pp = statX[cg * 8 + i];
            composed_norm(pp.x, pp.y, 4096.f, Av[i], Bv[i]);
        }
        ushort8 v;
#pragma unroll
        for (int i = 0; i < 8; i++) {
            float xv = x[(size_t)(cg * 8 + i) * 4096 + p];
            v[i] = f2bf(fmaf(xv, Av[i], Bv[i]));
        }
        *(ushort8*)&Xt16[(size_t)p * 256 + cg * 8] = v;
    }
}

// ---------------------------------------------------------------------------
// GEMM body (K-contig bf16 A[M][K] x B[N][K] -> bf16 P[M][N]).
// ---------------------------------------------------------------------------
template <int K>
__device__ void gemm_bt_body(const unsigned short* __restrict__ A,
                             const unsigned short* __restrict__ B,
                             unsigned short* __restrict__ P, int N,
                             int m0, int n0) {
    __shared__ short Ab[128 * 32];
    __shared__ short Bb[128 * 32];
    int tid = threadIdx.x;
    int lane = tid & 63, wid = tid >> 6;
    int mi = wid >> 1, ni = wid & 1;
    int l15 = lane & 15, khi = lane >> 4;

    floatx4 acc[4][4];
#pragma unroll
    for (int sm = 0; sm < 4; sm++)
#pragma unroll
        for (int sn = 0; sn < 4; sn++)
#pragma unroll
            for (int r = 0; r < 4; r++) acc[sm][sn][r] = 0.f;

    for (int kc = 0; kc < K / 32; kc++) {
        __syncthreads();
#pragma unroll
        for (int k = 0; k < 2; k++) {
            int s = k * 256 + tid;
            int row = s >> 2, q = s & 3;
            const unsigned short* ga = A + (size_t)(m0 + row) * K + kc * 32 + q * 8;
            __builtin_amdgcn_global_load_lds((glb_uint*)ga, (lds_uint*)(Ab + s * 8), 16, 0, 0);
            const unsigned short* gb = B + (size_t)(n0 + row) * K + kc * 32 + q * 8;
            __builtin_amdgcn_global_load_lds((glb_uint*)gb, (lds_uint*)(Bb + s * 8), 16, 0, 0);
        }
        __syncthreads();
        short8 a[4], b[4];
#pragma unroll
        for (int sm = 0; sm < 4; sm++)
            a[sm] = *(const short8*)&Ab[(mi * 64 + sm * 16 + l15) * 32 + khi * 8];
#pragma unroll
        for (int sn = 0; sn < 4; sn++)
            b[sn] = *(const short8*)&Bb[(ni * 64 + sn * 16 + l15) * 32 + khi * 8];
#pragma unroll
        for (int sm = 0; sm < 4; sm++)
#pragma unroll
            for (int sn = 0; sn < 4; sn++)
                acc[sm][sn] = __builtin_amdgcn_mfma_f32_16x16x32_bf16(
                    a[sm], b[sn], acc[sm][sn], 0, 0, 0);
    }
#pragma unroll
    for (int sm = 0; sm < 4; sm++)
#pragma unroll
        for (int sn = 0; sn < 4; sn++) {
            int m = m0 + mi * 64 + sm * 16 + khi * 4;
            int n = n0 + ni * 64 + sn * 16 + l15;
#pragma unroll
            for (int r = 0; r < 4; r++)
                P[(size_t)(m + r) * N + n] = f2bf(acc[sm][sn][r]);
        }
}

// MERGED: gemm16 [0,288) + Sp2 reduce [288,432) + Sp1 reduce [432,1008).
__launch_bounds__(256, 3)
__global__ void gemm16_red_kernel(const unsigned short* __restrict__ Wt16,
                                  const unsigned short* __restrict__ Xt16,
                                  unsigned short* __restrict__ P16,
                                  const float* __restrict__ Sp2, float* __restrict__ Sf2,
                                  const float* __restrict__ Sp1, float* __restrict__ Sf1) {
    int b = blockIdx.x;
    if (b < 288) {
        int n0 = (b & 31) << 7;
        int m0 = (b >> 5) << 7;
        gemm_bt_body<256>(Wt16, Xt16, P16, 4096, m0, n0);
    } else if (b < 432) {
        int i = (b - 288) * 256 + threadIdx.x;
        if (i < 36864) {
            float s = 0.f;
            for (int ch = 0; ch < 16; ch++) s += Sp2[(size_t)ch * 36864 + i];
            Sf2[i] = s;
        }
    } else {
        int i = (b - 432) * 256 + threadIdx.x;
        if (i < 147456) {
            float s = 0.f;
            for (int ch = 0; ch < 8; ch++) s += Sp1[(size_t)ch * 147456 + i];
            Sf1[i] = s;
        }
    }
}

// Plain gemm kernel for pac20.
template <int K>
__launch_bounds__(256, 3)
__global__ void gemm_bt_kernel(const unsigned short* __restrict__ A,
                               const unsigned short* __restrict__ B,
                               unsigned short* __restrict__ P, int N) {
    gemm_bt_body<K>(A, B, P, N, blockIdx.y << 7, blockIdx.x << 7);
}

// ---------------------------------------------------------------------------
// Fused DOUBLE instance-norm + transpose, planar-bf16 input (stage 1).
// ---------------------------------------------------------------------------
__global__ void transpose_norm2_bf16_kernel(const unsigned short* __restrict__ in,
                                            const float2* __restrict__ parts, int NB,
                                            unsigned short* __restrict__ xt,
                                            int C, int HW) {
    int t = blockIdx.x * blockDim.x + threadIdx.x;
    int p = t % HW;
    int cg = t / HW;
    float Av[8], Bv[8];
#pragma unroll
    for (int i = 0; i < 8; i++) {
        int c = cg * 8 + i;
        float s = 0.f, q = 0.f;
        for (int nb = 0; nb < NB; nb++) {
            float2 pp = parts[c * NB + nb];
            s += pp.x; q += pp.y;
        }
        composed_norm(s, q, (float)HW, Av[i], Bv[i]);
    }
    ushort8 v;
#pragma unroll
    for (int i = 0; i < 8; i++) {
        float x = bf2f(in[(size_t)(cg * 8 + i) * HW + p]);
        v[i] = f2bf(fmaf(x, Av[i], Bv[i]));
    }
    *(ushort8*)&xt[(size_t)p * C + cg * 8] = v;
}

// ---------------------------------------------------------------------------
// PAC combine, parity-pair form; planar bf16 out + raw stats partials.
// ---------------------------------------------------------------------------
__global__ void pac_combine2_kernel(const unsigned short* __restrict__ P,
                                    const float* __restrict__ S,
                                    const float* __restrict__ bias,
                                    unsigned short* __restrict__ out,
                                    float2* __restrict__ statOut,
                                    int O, int Hi, int Wi) {
    int HW4 = Hi * Wi;
    int Wo = Wi * 2;
    int HoWo = 4 * HW4;
    int idx = blockIdx.x * blockDim.x + threadIdx.x;
    int pixh = idx % HW4;
    int og = idx / HW4;
    int ys = pixh / Wi, xs = pixh % Wi;
    int ry = blockIdx.z;
    int y = 2 * ys + ry;
    bool xg = (xs + 1 < Wi);
    bool yg = (ys + 1 < Hi);
    size_t rowb = (size_t)ys * Wi + xs;

    float ev[4], ov[4];

    if (ry == 0) {
        float k3 = __expf(-0.5f * S[(size_t)3 * HW4 + pixh]);
        float k4 = __expf(-0.5f * S[(size_t)4 * HW4 + pixh]);
        float k5 = __expf(-0.5f * S[(size_t)5 * HW4 + pixh]);
#pragma unroll
        for (int r = 0; r < 4; r++) {
            int o = og * 4 + r;
            float bv = bias[o];
            const unsigned short* p3 = P + (size_t)(3 * O + o) * HW4 + rowb;
            const unsigned short* p4 = P + (size_t)(4 * O + o) * HW4 + rowb;
            const unsigned short* p5 = P + (size_t)(5 * O + o) * HW4 + rowb;
            float v4 = bf2f(p4[0]);
            float v3 = bf2f(p3[0]);
            float v5 = xg ? bf2f(p5[1]) : 0.f;
            ev[r] = bv + k4 * v4;
            ov[r] = bv + k3 * v3 + k5 * v5;
        }
    } else {
        float k0 = __expf(-0.5f * S[(size_t)0 * HW4 + pixh]);
        float k1 = __expf(-0.5f * S[(size_t)1 * HW4 + pixh]);
        float k2 = __expf(-0.5f * S[(size_t)2 * HW4 + pixh]);
        float k6 = __expf(-0.5f * S[(size_t)6 * HW4 + pixh]);
        float k7 = __expf(-0.5f * S[(size_t)7 * HW4 + pixh]);
        float k8 = __expf(-0.5f * S[(size_t)8 * HW4 + pixh]);
#pragma unroll
        for (int r = 0; r < 4; r++) {
            int o = og * 4 + r;
            float bv = bias[o];
            const unsigned short* p0 = P + (size_t)(0 * O + o) * HW4 + rowb;
            const unsigned short* p1 = P + (size_t)(1 * O + o) * HW4 + rowb;
            const unsigned short* p2 = P + (size_t)(2 * O + o) * HW4 + rowb;
            const unsigned short* p6 = P + (size_t)(6 * O + o) * HW4 + rowb + Wi;
            const unsigned short* p7 = P + (size_t)(7 * O + o) * HW4 + rowb + Wi;
            const unsigned short* p8 = P + (size_t)(8 * O + o) * HW4 + rowb + Wi;
            float v1 = bf2f(p1[0]);
            float v0 = bf2f(p0[0]);
            float v2 = xg ? bf2f(p2[1]) : 0.f;
            float v7 = yg ? bf2f(p7[0]) : 0.f;
            float v6 = yg ? bf2f(p6[0]) : 0.f;
            float v8 = (yg && xg) ? bf2f(p8[1]) : 0.f;
            ev[r] = bv + k1 * v1 + k7 * v7;
            ov[r] = bv + k0 * v0 + k2 * v2 + k6 * v6 + k8 * v8;
        }
    }
#pragma unroll
    for (int r = 0; r < 4; r++) {
        unsigned int pk = (unsigned int)f2bf(ev[r]) | ((unsigned int)f2bf(ov[r]) << 16);
        *(unsigned int*)&out[(size_t)(og * 4 + r) * HoWo + (size_t)y * Wo + 2 * xs] = pk;
    }

    __shared__ float rs[4][4], rq[4][4];
    int wave = threadIdx.x >> 6;
#pragma unroll
    for (int r = 0; r < 4; r++) {
        float s = ev[r] + ov[r];
        float q = ev[r] * ev[r] + ov[r] * ov[r];
#pragma unroll
        for (int off = 32; off >= 1; off >>= 1) {
            s += __shfl_down(s, off, 64);
            q += __shfl_down(q, off, 64);
        }
        if ((threadIdx.x & 63) == 0) { rs[wave][r] = s; rq[wave][r] = q; }
    }
    __syncthreads();
    if (threadIdx.x < 4) {
        int r = threadIdx.x;
        float s = rs[0][r] + rs[1][r] + rs[2][r] + rs[3][r];
        float q = rq[0][r] + rq[1][r] + rq[2][r] + rq[3][r];
        atomicAdd(&statOut[og * 4 + r].x, s);
        atomicAdd(&statOut[og * 4 + r].y, q);
    }
}

// ---------------------------------------------------------------------------
// Final conv with fused composed DOUBLE norm, planar-bf16 input.
// ---------------------------------------------------------------------------
__global__ void conv_part_norm_kernel(const unsigned short* __restrict__ in,
                                      const float* __restrict__ w,
                                      const float2* __restrict__ parts, int NB,
                                      float* __restrict__ Pf, int H, int W) {
    __shared__ float wsm[16 * 9 * 3];
    __shared__ float am[16], bm[16];
    int q0 = blockIdx.y * 16;
    int HW = H * W;
    for (int t = threadIdx.x; t < 432; t += blockDim.x) {
        int oc = t % 3;
        int tap = (t / 3) % 9;
        int c = t / 27;
        wsm[t] = w[((size_t)oc * 64 + q0 + c) * 9 + tap];
    }
    if (threadIdx.x < 16) {
        int c = q0 + threadIdx.x;
        float s = 0.f, q = 0.f;
        for (int nb = 0; nb < NB; nb++) {
            float2 pp = parts[c * NB + nb];
            s += pp.x; q += pp.y;
        }
        float A, B;
        composed_norm(s, q, (float)HW, A, B);
        am[threadIdx.x] = A;
        bm[threadIdx.x] = B;
    }
    __syncthreads();
    int pix = blockIdx.x * blockDim.x + threadIdx.x;
    int y = pix / W, x = pix % W;
    float acc[3] = {0.f, 0.f, 0.f};
    bool xl = (x > 0), xr = (x < W - 1);
    for (int c = 0; c < 16; c++) {
        const unsigned short* base = in + (size_t)(q0 + c) * HW + pix;
        const float* wc = wsm + c * 27;
        float ac = am[c], bc = bm[c];
#pragma unroll
        for (int dy = 0; dy < 3; dy++) {
            int yy = y + dy - 1;
            if (yy < 0 || yy >= H) continue;
            const unsigned short* row = base + (dy - 1) * W;
            float v0 = xl ? fmaf(bf2f(row[-1]), ac, bc) : 0.f;
            float v1 = fmaf(bf2f(row[0]), ac, bc);
            float v2 = xr ? fmaf(bf2f(row[1]), ac, bc) : 0.f;
#pragma unroll
            for (int ob = 0; ob < 3; ob++) {
                acc[ob] += v0 * wc[(dy * 3 + 0) * 3 + ob];
                acc[ob] += v1 * wc[(dy * 3 + 1) * 3 + ob];
                acc[ob] += v2 * wc[(dy * 3 + 2) * 3 + ob];
            }
        }
    }
#pragma unroll
    for (int ob = 0; ob < 3; ob++)
        Pf[(size_t)(blockIdx.y * 3 + ob) * HW + pix] = acc[ob];
}

__global__ void conv_fin_kernel(const float* __restrict__ Pf, const float* __restrict__ bias,
                                float* __restrict__ out, int HW) {
    int pix = blockIdx.x * blockDim.x + threadIdx.x;
#pragma unroll
    for (int ob = 0; ob < 3; ob++) {
        float a = bias[ob];
#pragma unroll
        for (int q = 0; q < 4; q++)
            a += Pf[(size_t)(q * 3 + ob) * HW + pix];
        out[(size_t)ob * HW + pix] = a;
    }
}

// ---------------------------------------------------------------------------
extern "C" void kernel_launch(void* const* d_in, const int* in_sizes, int n_in,
                              void* d_out, int out_size, void* d_ws, size_t ws_size,
                              hipStream_t stream) {
    const float* x      = (const float*)d_in[0];   // (256,64,64)
    const float* ef2    = (const float*)d_in[1];   // (128,128,128)
    const float* ef1    = (const float*)d_in[2];   // (64,256,256)
    const float* w_adj2 = (const float*)d_in[3];
    const float* b_adj2 = (const float*)d_in[4];
    const float* w_adj1 = (const float*)d_in[5];
    const float* b_adj1 = (const float*)d_in[6];
    const float* w_p16  = (const float*)d_in[7];
    const float* b_p16  = (const float*)d_in[8];
    const float* w_p20  = (const float*)d_in[9];
    const float* b_p20  = (const float*)d_in[10];
    const float* w_out  = (const float*)d_in[11];
    const float* b_out  = (const float*)d_in[12];
    float* out = (float*)d_out;                    // (3,256,256)

    // ---- workspace layout (float offsets) ----
    float* ws = (float*)d_ws;
    unsigned short* bxb1 = (unsigned short*)(ws + 1048576);   // bf16
    unsigned short* bxb2 = (unsigned short*)(ws + 3145728);   // bf16
    unsigned short* Wt16 = (unsigned short*)(ws + 5242880);
    unsigned short* Xt16 = (unsigned short*)(ws + 5390336);
    float* bk2c = ws + 7340032;
    float* bk1c = ws + 7376896;
    float2* statX   = (float2*)(ws + 7524352);
    float2* statP16 = (float2*)(ws + 7525376);
    float2* statP20 = (float2*)(ws + 7526656);
    unsigned short* Wt20 = (unsigned short*)(ws + 7528832);
    unsigned short* Gp1  = (unsigned short*)(ws + 7569792);
    unsigned short* P16  = (unsigned short*)(ws + 7569792);
    unsigned short* P20  = (unsigned short*)(ws + 7569792);
    unsigned short* Gp2  = (unsigned short*)(ws + 12812672);
    unsigned short* Xt20 = (unsigned short*)(ws + 12812672);
    unsigned short* Xp2 = (unsigned short*)(ws + 14975872);
    unsigned short* Wr2 = (unsigned short*)(ws + 16057472);
    unsigned short* Xp1 = (unsigned short*)(ws + 16204928);
    unsigned short* Wr1 = (unsigned short*)(ws + 18334976);
    float* Pf = ws + 14975872;
    float* Sp2 = ws + 18371840;
    float* Sp1 = ws + 18961664;

    // K1: PROLOGUE
    prologue_kernel<<<3756, 256, 0, stream>>>(
        (uint4v*)(ws + 7525376), Xp2, Xp1,
        w_adj2, Wr2, w_adj1, Wr1, w_p16, Wt16, w_p20, Wt20,
        ef2, ef1, x, statX);

    // K2: both guide convs (all-tap, 2-row tiles: 128 g2 + 256 g1 blocks)
    conv_both_kernel<<<384, 256, 0, stream>>>(Xp2, Wr2, b_adj2, Gp2,
                                              Xp1, Wr1, b_adj1, Gp1);

    // K3: kk2 + kk1 + stage-0 transpose
    kk_both_transpose_kernel<<<2048, 256, 0, stream>>>(Gp2, Sp2, Gp1, Sp1, x, statX, Xt16);

    // K4: gemm16 + Sp2 reduce + Sp1 reduce
    gemm16_red_kernel<<<1008, 256, 0, stream>>>(Wt16, Xt16, P16, Sp2, bk2c, Sp1, bk1c);

    // K5: combine16 -> bxb1 + statP16
    pac_combine2_kernel<<<dim3(512, 1, 2), 256, 0, stream>>>(P16, bk2c, b_p16, bxb1, statP16, 128, 64, 64);

    // K6: stage-1 double-norm transpose (bf16 in)
    transpose_norm2_bf16_kernel<<<1024, 256, 0, stream>>>(bxb1, statP16, 1, Xt20, 128, 16384);

    // K7: gemm20
    gemm_bt_kernel<128><<<dim3(128, 5), 256, 0, stream>>>(Wt20, Xt20, P20, 16384);

    // K8: combine20 -> bxb2 + statP20
    pac_combine2_kernel<<<dim3(1024, 1, 2), 256, 0, stream>>>(P20, bk1c, b_p20, bxb2, statP20, 64, 128, 128);

    // K9/K10: final conv (norm fused) + sum
    conv_part_norm_kernel<<<dim3(256, 4), 256, 0, stream>>>(bxb2, w_out, statP20, 1, Pf, 256, 256);
    conv_fin_kernel<<<256, 256, 0, stream>>>(Pf, b_out, out, 65536);
}